// Round 1
// baseline (258.106 us; speedup 1.0000x reference)
//
#include <hip/hip_runtime.h>

// LongformerAttention on MI355X (gfx950), fp16 MFMA pipeline, round 8.
// R8: QKV and out-proj GEMMs rewritten from the m97-class 128^2 structure
// (stage -> syncthreads(vmcnt0 drain) -> compute, 609 TF, MfmaUtil 25%) to a
// 256x128-tile, BK=32, 3-buffer-deep pipeline with counted vmcnt:
//   - 3 LDS buffers (72 KB): while computing tile T, stage tile T+2. The
//     per-tile wait (vmcnt(9): keep T+1's 6 + T+2's 3 in flight) targets
//     loads issued ~2.5 phases (~1100 cyc) earlier -> HBM latency covered,
//     queue never drains except at the final tile.
//   - raw s_barrier + inline-asm s_waitcnt (no __syncthreads in hot loop);
//     s_setprio(1) around each 16-MFMA cluster (T5, pays only in phase-split
//     schedules).
//   - per-wave 128x64 output (acc[8][4]); 256 threads/block, ~190 VGPR ->
//     2 blocks/CU co-resident (LDS 2x72KB, launch_bounds(256,2)).
//   - grid: qkv 768 blocks = exactly 3 full CU rounds; out 256 = 1 round.
//     XCD swizzle gives each XCD a 2MB A-panel + 2MB B (fits 4MB L2).
//   - BK=32 k-chunk swizzle: phys chunk = quad ^ ((row>>1)&3); verified
//     conflict-free for ds_read_b128 (row stride 64B: granule = 4*(l4&1) +
//     (quad^((l4>>1)&3)) covers all 8 16B-granules evenly). Stage = linear
//     LDS dest + inverse-swizzled global source (both-sides-or-neither).
// Epilogues (RoPE/bias/V^T, LDS-tiled coalesced stores) functionally as R7,
// re-indexed for the 256-row tile in two wm-halves. Attention & convert
// kernels unchanged from R7.

typedef _Float16 half8 __attribute__((ext_vector_type(8)));
typedef _Float16 half4v __attribute__((ext_vector_type(4)));
typedef float floatx4 __attribute__((ext_vector_type(4)));

typedef __attribute__((address_space(3))) unsigned int lds_u32;
typedef const __attribute__((address_space(1))) unsigned int glb_u32;

__device__ __forceinline__ void async_copy16(const void* g, void* l) {
  // global -> LDS direct, 16 B/lane. LDS dest = wave-uniform base + lane*16.
  __builtin_amdgcn_global_load_lds((glb_u32*)g, (lds_u32*)l, 16, 0, 0);
}

// ---------------------------------------------------------------- convert
__global__ __launch_bounds__(256) void convert_kernel(
    const float* __restrict__ x, const float* __restrict__ wq,
    const float* __restrict__ wk, const float* __restrict__ wv,
    const float* __restrict__ wo, _Float16* __restrict__ dst) {
  const int e0 = (blockIdx.x * 256 + threadIdx.x) * 4;
  const float* src; int off;
  if      (e0 <  8388608) { src = x;  off = e0; }
  else if (e0 <  9437184) { src = wq; off = e0 -  8388608; }
  else if (e0 < 10485760) { src = wk; off = e0 -  9437184; }
  else if (e0 < 11534336) { src = wv; off = e0 - 10485760; }
  else                    { src = wo; off = e0 - 11534336; }
  const float4 f = *(const float4*)(src + off);
  half4v h;
  h[0] = (_Float16)f.x; h[1] = (_Float16)f.y;
  h[2] = (_Float16)f.z; h[3] = (_Float16)f.w;
  *(half4v*)(dst + e0) = h;
}

// ---------------------------------------------------- 256x128 GEMM main loop
// out[m,n] = sum_k A[m,k]*B[n,k], M-tile 256, N-tile 128, BK=32, K=1024.
// 4 waves: wm = w&1 (m-half), wn = w>>1 (n-quarter 0..1); per-wave 128x64.
// LDS per buffer: A 256x32 (8192 halfs) + B 128x32 (4096) = 12288 halfs.
// 3 buffers rotate; tile T in buf T%3; T+2 staged into (T+2)%3 during T.
// Per tile 2 phases of 16 MFMA; stage 3 loads/thread/phase (A:2, B:1).
__device__ __forceinline__ void gemm256_mainloop(
    const _Float16* __restrict__ Ag, const _Float16* __restrict__ Bg,
    _Float16* smem, const int m0, const int n0, floatx4 (&acc)[8][4]) {
  const int tid = threadIdx.x;
  const int w = tid >> 6, lane = tid & 63;
  const int l4 = lane & 15, quad = lane >> 4;
  const int wm = w & 1, wn = w >> 1;

  // per-thread stage source offsets (halfs). LDS is linear in position p;
  // global source chunk = (p&3) ^ ((row>>1)&3) (inverse of the read swizzle).
  int srcA[4], srcB[2];
#pragma unroll
  for (int i = 0; i < 4; ++i) {
    const int p = i * 256 + tid;
    const int r = p >> 2;
    const int g = (p & 3) ^ ((r >> 1) & 3);
    srcA[i] = (m0 + r) * 1024 + g * 8;
  }
#pragma unroll
  for (int i = 0; i < 2; ++i) {
    const int p = i * 256 + tid;
    const int r = p >> 2;
    const int g = (p & 3) ^ ((r >> 1) & 3);
    srcB[i] = (n0 + r) * 1024 + g * 8;
  }
  const int dstw = w * 512;  // wave-uniform LDS dest base (halfs), + i*2048

  // ds_read offsets: row = (wm*128|wn*64) + sub*16 + l4, chunk = quad ^ ((l4>>1)&3)
  const int swz = (quad ^ ((l4 >> 1) & 3)) * 8;
  const int a_off = (wm * 128 + l4) * 32 + swz;
  const int b_off = (wn * 64 + l4) * 32 + swz;

  const floatx4 zero = {0.f, 0.f, 0.f, 0.f};
#pragma unroll
  for (int i = 0; i < 8; ++i)
#pragma unroll
    for (int j = 0; j < 4; ++j) acc[i][j] = zero;

  // stage(bufbase, kt, phase): phase 0 -> A rows 0..127 + B rows 0..63;
  //                            phase 1 -> A rows 128..255 + B rows 64..127.
  auto stage = [&](int bufbase, int kt, int ph) {
    _Float16* Ad = smem + bufbase;
    _Float16* Bd = Ad + 8192;
    const int k0 = kt * 32;
    if (ph == 0) {
      async_copy16(Ag + srcA[0] + k0, Ad + dstw);
      async_copy16(Ag + srcA[1] + k0, Ad + 2048 + dstw);
      async_copy16(Bg + srcB[0] + k0, Bd + dstw);
    } else {
      async_copy16(Ag + srcA[2] + k0, Ad + 4096 + dstw);
      async_copy16(Ag + srcA[3] + k0, Ad + 6144 + dstw);
      async_copy16(Bg + srcB[1] + k0, Bd + 2048 + dstw);
    }
  };

  // prologue: tiles 0 -> buf0, 1 -> buf1 (12 loads in flight)
  stage(0, 0, 0);     stage(0, 0, 1);
  stage(12288, 1, 0); stage(12288, 1, 1);

  int cb_ = 0, nb_ = 24576;  // buf offsets for tile t and t+2
  for (int t = 0; t < 32; ++t) {
    _Float16* Ac = smem + cb_;
    _Float16* Bc = Ac + 8192;

    // ---- phase 0: issue T+2 slot 0, wait for T's 6 loads, compute m0..3 ----
    if (t < 30) {
      stage(nb_, t + 2, 0);
      asm volatile("s_waitcnt vmcnt(9)" ::: "memory");   // T+1(6)+T+2(3) in flight
    } else if (t == 30) {
      asm volatile("s_waitcnt vmcnt(6)" ::: "memory");   // T+1(6) in flight
    } else {
      asm volatile("s_waitcnt vmcnt(0)" ::: "memory");   // last tile: drain
    }
    __builtin_amdgcn_s_barrier();

    half8 af[4], bf[4];
#pragma unroll
    for (int mt = 0; mt < 4; ++mt) af[mt] = *(const half8*)(Ac + a_off + mt * 512);
#pragma unroll
    for (int nt = 0; nt < 4; ++nt) bf[nt] = *(const half8*)(Bc + b_off + nt * 512);
    __builtin_amdgcn_s_setprio(1);
#pragma unroll
    for (int mt = 0; mt < 4; ++mt)
#pragma unroll
      for (int nt = 0; nt < 4; ++nt)
        acc[mt][nt] = __builtin_amdgcn_mfma_f32_16x16x32_f16(af[mt], bf[nt], acc[mt][nt], 0, 0, 0);
    __builtin_amdgcn_s_setprio(0);
    __builtin_amdgcn_s_barrier();

    // ---- phase 1: read m4..7, issue T+2 slot 1, compute m4..7 ----
#pragma unroll
    for (int mt = 0; mt < 4; ++mt) af[mt] = *(const half8*)(Ac + a_off + (mt + 4) * 512);
    if (t < 30) stage(nb_, t + 2, 1);
    __builtin_amdgcn_s_barrier();
    __builtin_amdgcn_s_setprio(1);
#pragma unroll
    for (int mt = 0; mt < 4; ++mt)
#pragma unroll
      for (int nt = 0; nt < 4; ++nt)
        acc[mt + 4][nt] = __builtin_amdgcn_mfma_f32_16x16x32_f16(af[mt], bf[nt], acc[mt + 4][nt], 0, 0, 0);
    __builtin_amdgcn_s_setprio(0);
    __builtin_amdgcn_s_barrier();

    cb_ += 12288; if (cb_ == 36864) cb_ = 0;
    nb_ += 12288; if (nb_ == 36864) nb_ = 0;
  }
}

// ---------------------------------------------------------------- QKV GEMM
// grid 768 = 8 XCD x (3 z x 4 m x 8 n); per-XCD: 4 m-panels x full B per z.
// RoPE fused for q,k (pair (n,n^1) adjacent l4 lanes); q scaled log2e/8.
// z==2 (V): epilogue tile transposed, output written as V^T [bh][d][s].
__global__ __launch_bounds__(256, 2) void gemm_qkv_kernel(
    const _Float16* __restrict__ A, const _Float16* __restrict__ w0,
    const _Float16* __restrict__ w1, const _Float16* __restrict__ w2,
    const float* __restrict__ b0, const float* __restrict__ b1,
    const float* __restrict__ b2, _Float16* __restrict__ o0,
    _Float16* __restrict__ o1, _Float16* __restrict__ o2) {
  __shared__ _Float16 smem[36864];          // 3 x 24 KB staging / epi 33.8 KB

  const int tid = threadIdx.x;
  const int w = tid >> 6, lane = tid & 63;
  const int l4 = lane & 15, quad = lane >> 4;
  const int wm = w & 1, wn = w >> 1;

  const int bid = blockIdx.x;
  const int xcd = bid & 7, li = bid >> 3;   // li in 0..95
  const int z = li >> 5, li_z = li & 31;
  const int m0 = (xcd * 4 + (li_z & 3)) * 256;
  const int n0 = (li_z >> 2) * 128;

  const _Float16* B; const float* bias; _Float16* out;
  if (z == 0)      { B = w0; bias = b0; out = o0; }
  else if (z == 1) { B = w1; bias = b1; out = o1; }
  else             { B = w2; bias = b2; out = o2; }
  const bool dorope = z < 2;
  const float scl = (z == 0) ? 0.18033688f : 1.0f;  // log2e/8

  floatx4 acc[8][4];
  gemm256_mainloop(A, B, smem, m0, n0, acc);

  // epilogue in two m-halves (waves wm==h own rows h*128..h*128+127).
  // q,k: tile[ml][nl] -> [bh][s][d]. V: tile[nl][ml] -> V^T [bh][d][s].
  _Float16* tile = smem;                    // [128][132]
  for (int h = 0; h < 2; ++h) {
    if (wm == h) {
#pragma unroll
      for (int nt = 0; nt < 4; ++nt) {
        const int n = n0 + wn * 64 + nt * 16 + l4;
        const float bval = bias[n];
        const int hh = n >> 6;
        float c_ = 1.f, ss = 0.f;
        if (dorope) {
          const float freq = __expf((float)(n & 31) * -0.28782314f);  // ln(1e4)/32
          float s_;
          __sincosf((float)hh * freq, &s_, &c_);
          ss = (n & 1) ? s_ : -s_;
        }
#pragma unroll
        for (int mt = 0; mt < 8; ++mt)
#pragma unroll
          for (int r = 0; r < 4; ++r) {
            float val = acc[mt][nt][r] + bval;
            const float prt = __shfl_xor(val, 1);
            if (dorope) val = (val * c_ + prt * ss) * scl;
            const int ml = mt * 16 + quad * 4 + r;
            const int nl = wn * 64 + nt * 16 + l4;
            if (z == 2) tile[nl * 132 + ml] = (_Float16)val;   // transposed
            else        tile[ml * 132 + nl] = (_Float16)val;
          }
      }
    }
    __syncthreads();

    const int mg = m0 + h * 128;
    const int bb = mg >> 12, sg = mg & 4095;
    if (z == 2) {
#pragma unroll
      for (int tt = 0; tt < 8; ++tt) {
        const int idx = tt * 256 + tid;     // 128 d-rows x 16 s-chunks
        const int rr = idx >> 4, cbk = idx & 15;
        const int n = n0 + rr, hh2 = n >> 6, dd = n & 63;
        const int s = sg + cbk * 8;
        const half8 vals = *(const half8*)(tile + rr * 132 + cbk * 8);
        *(half8*)(out + (bb * 16 + hh2) * 262144 + dd * 4096 + s) = vals;
      }
    } else {
#pragma unroll
      for (int tt = 0; tt < 8; ++tt) {
        const int idx = tt * 256 + tid;     // 128 s-rows x 16 d-chunks
        const int rr = idx >> 4, cbk = idx & 15;
        const int n = n0 + cbk * 8, hh2 = n >> 6, dd = n & 63;
        const int s = sg + rr;
        const half8 vals = *(const half8*)(tile + rr * 132 + cbk * 8);
        *(half8*)(out + ((bb * 16 + hh2) * 4096 + s) * 64 + dd) = vals;
      }
    }
    __syncthreads();
  }
}

// ---------------------------------------------------------------- out GEMM
// grid 256 = 8 XCD x (4 m x 8 n): one full CU round.
__global__ __launch_bounds__(256, 2) void gemm_out_kernel(
    const _Float16* __restrict__ A, const _Float16* __restrict__ B,
    const float* __restrict__ bias, float* __restrict__ out) {
  __shared__ _Float16 smem[36864];

  const int tid = threadIdx.x;
  const int w = tid >> 6, lane = tid & 63;
  const int l4 = lane & 15, quad = lane >> 4;
  const int wm = w & 1, wn = w >> 1;

  const int bid = blockIdx.x;
  const int xcd = bid & 7, li = bid >> 3;   // li in 0..31
  const int m0 = (xcd * 4 + (li & 3)) * 256;
  const int n0 = (li >> 2) * 128;

  floatx4 acc[8][4];
  gemm256_mainloop(A, B, smem, m0, n0, acc);

#pragma unroll
  for (int nt = 0; nt < 4; ++nt) {
    const int n = n0 + wn * 64 + nt * 16 + l4;
    const float bval = bias[n];
#pragma unroll
    for (int mt = 0; mt < 8; ++mt)
#pragma unroll
      for (int r = 0; r < 4; ++r) {
        const int m = m0 + wm * 128 + mt * 16 + quad * 4 + r;
        out[m * 1024 + n] = acc[mt][nt][r] + bval;
      }
  }
}

// ---------------------------------------------------------------- attention
// Unchanged from R7. S^T formulation: ST = K*Q^T per 64-key half-tile; ST
// C-layout IS the B-operand layout of mfma_f32_16x16x16f16 -> P feeds PV
// from registers. 256 queries/block (2 subs of 128), 6 kv-tiles.
// Softmax: STATIC shift P = exp2(S-4); no running max / rescale; l
// accumulated lane-locally, cross-quad reduced at the end.
__global__ __launch_bounds__(256, 2) void attn_kernel(
    const _Float16* __restrict__ qg, const _Float16* __restrict__ kg,
    const _Float16* __restrict__ vtg, _Float16* __restrict__ ctx) {
  __shared__ _Float16 Ks[128 * 64];   // [key][d]
  __shared__ _Float16 Vs[64 * 128];   // [d][key] (from vt)

  const int tid = threadIdx.x;
  const int w = tid >> 6, lane = tid & 63;
  const int l4 = lane & 15, quad = lane >> 4;
  const int q0 = blockIdx.x * 256;
  const int bh = blockIdx.y;
  const _Float16* qbh = qg + bh * 262144;
  const _Float16* kbh = kg + bh * 262144;
  const _Float16* vbh = vtg + bh * 262144;

  // Q as B-operand frags: query = q0 + sub*128 + w*32 + nt*16 + l4
  half8 qf[2][2][2];
#pragma unroll
  for (int sub = 0; sub < 2; ++sub)
#pragma unroll
    for (int nt = 0; nt < 2; ++nt)
#pragma unroll
      for (int ks = 0; ks < 2; ++ks)
        qf[sub][nt][ks] = *(const half8*)(qbh + (q0 + sub * 128 + w * 32 + nt * 16 + l4) * 64 +
                                          ks * 32 + quad * 8);

  const floatx4 zero = {0.f, 0.f, 0.f, 0.f};
  floatx4 OT[2][4][2];               // [sub][d-tile][q-tile]
  float l_st[2][2];                  // lane-local partial (this quad's keys)
#pragma unroll
  for (int sub = 0; sub < 2; ++sub) {
#pragma unroll
    for (int md = 0; md < 4; ++md)
#pragma unroll
      for (int nt = 0; nt < 2; ++nt) OT[sub][md][nt] = zero;
#pragma unroll
    for (int nt = 0; nt < 2; ++nt) l_st[sub][nt] = 0.f;
  }

  for (int t = 0; t < 6; ++t) {
    const int kv0 = q0 - 256 + t * 128;
    if (kv0 < 0 || kv0 >= 4096) continue;  // block-uniform

#pragma unroll
    for (int i = 0; i < 4; ++i) {
      const int p = i * 256 + tid;
      const int rk = p >> 3, ck = (p & 7) ^ (rk & 7);
      async_copy16(kbh + (kv0 + rk) * 64 + ck * 8, Ks + (i * 256 + w * 64) * 8);
      const int rv = p >> 4, cv = (p & 15) ^ (rv & 7);
      async_copy16(vbh + rv * 4096 + kv0 + cv * 8, Vs + (i * 256 + w * 64) * 8);
    }
    __syncthreads();

#pragma unroll
    for (int sub = 0; sub < 2; ++sub) {
      // band geometry (d = key - query, valid iff |d| <= 256)
      if ((t == 0 && sub == 1) || (t == 5 && sub == 0)) continue;
      const bool needmask = (t == 0 && sub == 0) || (t == 1 && sub == 1) ||
                            (t == 4 && sub == 0) || (t == 5 && sub == 1);
      const int qbase = q0 + sub * 128 + w * 32;

#pragma unroll
      for (int hf = 0; hf < 2; ++hf) {
        const int kb = hf * 64;

        floatx4 ST[4][2];
#pragma unroll
        for (int m = 0; m < 4; ++m)
#pragma unroll
          for (int nt = 0; nt < 2; ++nt) ST[m][nt] = zero;
#pragma unroll
        for (int ks = 0; ks < 2; ++ks)
#pragma unroll
          for (int m = 0; m < 4; ++m) {
            const half8 kf = *(const half8*)(Ks + (kb + m * 16 + l4) * 64 +
                                             ((ks * 4 + quad) ^ (l4 & 7)) * 8);
#pragma unroll
            for (int nt = 0; nt < 2; ++nt)
              ST[m][nt] = __builtin_amdgcn_mfma_f32_16x16x32_f16(kf, qf[sub][nt][ks], ST[m][nt], 0, 0, 0);
          }

        if (needmask) {  // band mask |key - query| <= 256
#pragma unroll
          for (int m = 0; m < 4; ++m)
#pragma unroll
            for (int r = 0; r < 4; ++r) {
              const int key = kv0 + kb + m * 16 + quad * 4 + r;
#pragma unroll
              for (int nt = 0; nt < 2; ++nt) {
                const int d = key - (qbase + nt * 16 + l4);
                if (d < -256 || d > 256) ST[m][nt][r] = -1e30f;
              }
            }
        }

        // P = exp2(S - 4); lane-local l accumulation (no max, no rescale)
#pragma unroll
        for (int nt = 0; nt < 2; ++nt) {
          float rs = 0.f;
#pragma unroll
          for (int m = 0; m < 4; ++m)
#pragma unroll
            for (int r = 0; r < 4; ++r) {
              const float pv = exp2f(ST[m][nt][r] - 4.0f);
              ST[m][nt][r] = pv;
              rs += pv;
            }
          l_st[sub][nt] += rs;
        }

        // O^T += V^T P^T; P B-frag = packed ST C-frag (k=quad*4+j)
#pragma unroll
        for (int m = 0; m < 4; ++m) {
          half4v pb[2];
#pragma unroll
          for (int nt = 0; nt < 2; ++nt) {
            const auto lo = __builtin_amdgcn_cvt_pkrtz(ST[m][nt][0], ST[m][nt][1]);
            const auto hi = __builtin_amdgcn_cvt_pkrtz(ST[m][nt][2], ST[m][nt][3]);
            pb[nt][0] = (_Float16)lo[0]; pb[nt][1] = (_Float16)lo[1];
            pb[nt][2] = (_Float16)hi[0]; pb[nt][3] = (_Float16)hi[1];
          }
#pragma unroll
          for (int md = 0; md < 4; ++md) {
            const half4v vf = *(const half4v*)(Vs + (md * 16 + l4) * 128 +
                                               (((hf * 8 + m * 2 + (quad >> 1)) ^ (l4 & 7)) * 8 +
                                                (quad & 1) * 4));
#pragma unroll
            for (int nt = 0; nt < 2; ++nt)
              OT[sub][md][nt] = __builtin_amdgcn_mfma_f32_16x16x16f16(vf, pb[nt], OT[sub][md][nt], 0, 0, 0);
          }
        }
      }
    }
    __syncthreads();  // protect Ks/Vs before next tile's staging
  }

  // epilogue: reduce l across quads (keys were quad-distributed), then scale.
  const int b = bh >> 4, hh = bh & 15;
#pragma unroll
  for (int sub = 0; sub < 2; ++sub)
#pragma unroll
    for (int nt = 0; nt < 2; ++nt) {
      float lt = l_st[sub][nt];
      lt += __shfl_xor(lt, 16);
      lt += __shfl_xor(lt, 32);
      const float inv_l = 1.f / lt;
      const int s = q0 + sub * 128 + w * 32 + nt * 16 + l4;
#pragma unroll
      for (int md = 0; md < 4; ++md) {
        half4v o;
#pragma unroll
        for (int r = 0; r < 4; ++r) o[r] = (_Float16)(OT[sub][md][nt][r] * inv_l);
        *(half4v*)(ctx + (b * 4096 + s) * 1024 + hh * 64 + md * 16 + quad * 4) = o;
      }
    }
}

// ---------------------------------------------------------------- launch
extern "C" void kernel_launch(void* const* d_in, const int* in_sizes, int n_in,
                              void* d_out, int out_size, void* d_ws, size_t ws_size,
                              hipStream_t stream) {
  const float* x  = (const float*)d_in[0];
  const float* Wq = (const float*)d_in[1];
  const float* bq = (const float*)d_in[2];
  const float* Wk = (const float*)d_in[3];
  const float* bk = (const float*)d_in[4];
  const float* Wv = (const float*)d_in[5];
  const float* bv = (const float*)d_in[6];
  const float* Wo = (const float*)d_in[7];
  const float* bo = (const float*)d_in[8];

  _Float16* ws   = (_Float16*)d_ws;       // all offsets in halfs
  _Float16* xh   = ws;                    // 8388608
  _Float16* wqh  = ws + 8388608;          // 1048576 each
  _Float16* wkh  = ws + 9437184;
  _Float16* wvh  = ws + 10485760;
  _Float16* woh  = ws + 11534336;
  _Float16* qh   = ws + 12582912;         // [b,h,s,d] fp16, rope+scale applied
  _Float16* kh   = ws + 20971520;         // [b,h,s,d] fp16, rope applied
  _Float16* vth  = ws + 29360128;         // [b,h,d,s] fp16 (written directly)
  _Float16* ctxh = xh;                    // reuse: x dead after QKV GEMM

  convert_kernel<<<12288, 256, 0, stream>>>(x, Wq, Wk, Wv, Wo, ws);
  gemm_qkv_kernel<<<768, 256, 0, stream>>>(xh, wqh, wkh, wvh,
                                           bq, bk, bv, qh, kh, vth);
  attn_kernel<<<dim3(16, 32), 256, 0, stream>>>(qh, kh, vth, ctxh);
  gemm_out_kernel<<<256, 256, 0, stream>>>(ctxh, woh, bo, (float*)d_out);
}

// Round 2
// 253.453 us; speedup vs baseline: 1.0184x; 1.0184x over previous
//
#include <hip/hip_runtime.h>

// LongformerAttention on MI355X (gfx950), fp16 MFMA pipeline, round 9.
// R9: GEMMs reverted verbatim to R7 (R8's 3-buffer deep pipeline REGRESSED:
// 72KB LDS halved co-residency 4->2 blocks/CU, occupancy 30->17%, MfmaUtil
// 25->22.6% -- the implicit wave-level overlap beat the explicit pipeline).
// Attention reworked instead (was VALU-bound, 53% VALUBusy / 21% Mfma, and
// grid-limited to 2 blocks/CU):
//   - 128 queries/block -> grid 1024 = exactly 4 blocks/CU (16 waves/CU,
//     2x occupancy); launch_bounds(256,4) caps VGPR at 128 (usage ~112).
//   - XCD-swizzled bh mapping: xcd=bid&7 owns 4 heads -> per-XCD KV working
//     set 4MB = L2 capacity; KV staging becomes L2-resident.
//   - exact wave-uniform band tests replace the static (t,sub) table: skip
//     64-key half-tiles fully outside |d|<=256 for this wave's 32 queries
//     (computed keys/query 640 -> ~576), mask VALU only on true straddles.
// Same static-shift softmax P = exp2(S-4) (no max/rescale), lane-local l.

typedef _Float16 half8 __attribute__((ext_vector_type(8)));
typedef _Float16 half4v __attribute__((ext_vector_type(4)));
typedef float floatx4 __attribute__((ext_vector_type(4)));

typedef __attribute__((address_space(3))) unsigned int lds_u32;
typedef const __attribute__((address_space(1))) unsigned int glb_u32;

__device__ __forceinline__ void async_copy16(const void* g, void* l) {
  // global -> LDS direct, 16 B/lane. LDS dest = wave-uniform base + lane*16.
  __builtin_amdgcn_global_load_lds((glb_u32*)g, (lds_u32*)l, 16, 0, 0);
}

// ---------------------------------------------------------------- convert
__global__ __launch_bounds__(256) void convert_kernel(
    const float* __restrict__ x, const float* __restrict__ wq,
    const float* __restrict__ wk, const float* __restrict__ wv,
    const float* __restrict__ wo, _Float16* __restrict__ dst) {
  const int e0 = (blockIdx.x * 256 + threadIdx.x) * 4;
  const float* src; int off;
  if      (e0 <  8388608) { src = x;  off = e0; }
  else if (e0 <  9437184) { src = wq; off = e0 -  8388608; }
  else if (e0 < 10485760) { src = wk; off = e0 -  9437184; }
  else if (e0 < 11534336) { src = wv; off = e0 - 10485760; }
  else                    { src = wo; off = e0 - 11534336; }
  const float4 f = *(const float4*)(src + off);
  half4v h;
  h[0] = (_Float16)f.x; h[1] = (_Float16)f.y;
  h[2] = (_Float16)f.z; h[3] = (_Float16)f.w;
  *(half4v*)(dst + e0) = h;
}

// ---------------------------------------------------------------- QKV GEMM
// out[m,n] = sum_k A[m,k]*W[n,k] + bias[n]; RoPE fused in epilogue for q,k
// (pair (n,n^1) in adjacent l4 lanes -> __shfl_xor(val,1)); q scaled log2e/8.
// z==2 (V): epilogue LDS tile stored transposed, output written as V^T
// [bh][d][s] directly.
__global__ __launch_bounds__(256, 2) void gemm_qkv_kernel(
    const _Float16* __restrict__ A, const _Float16* __restrict__ w0,
    const _Float16* __restrict__ w1, const _Float16* __restrict__ w2,
    const float* __restrict__ b0, const float* __restrict__ b1,
    const float* __restrict__ b2, _Float16* __restrict__ o0,
    _Float16* __restrict__ o1, _Float16* __restrict__ o2) {
  __shared__ _Float16 smem[17408];          // staging 32 KB / epi tile 33.8 KB
  _Float16* As = smem;                      // [128][64] chunk-swizzled
  _Float16* Bs = smem + 8192;

  const int tid = threadIdx.x;
  const int w = tid >> 6, lane = tid & 63;
  const int l4 = lane & 15, quad = lane >> 4;
  const int wm = w & 1, wn = w >> 1;

  const int bid = blockIdx.x;
  const int xcd = bid & 7, li = bid >> 3;   // li in 0..191
  const int z = li >> 6, r_ = li & 63;
  const int n_l = r_ >> 3, m_l = r_ & 7;
  const int m0 = (xcd * 8 + m_l) * 128;
  const int n0 = n_l * 128;

  const _Float16* B; const float* bias; _Float16* out;
  if (z == 0)      { B = w0; bias = b0; out = o0; }
  else if (z == 1) { B = w1; bias = b1; out = o1; }
  else             { B = w2; bias = b2; out = o2; }
  const bool dorope = z < 2;
  const float scl = (z == 0) ? 0.18033688f : 1.0f;  // log2e/8

  const floatx4 zero = {0.f, 0.f, 0.f, 0.f};
  floatx4 acc[4][4];
#pragma unroll
  for (int i = 0; i < 4; ++i)
#pragma unroll
    for (int j = 0; j < 4; ++j) acc[i][j] = zero;

  for (int kt = 0; kt < 16; ++kt) {
    const int k0 = kt * 64;
#pragma unroll
    for (int i = 0; i < 4; ++i) {
      const int p = i * 256 + tid;          // 128 rows x 8 chunks
      const int r = p >> 3;
      const int c = (p & 7) ^ (r & 7);      // 3-bit XOR chunk swizzle
      async_copy16(A + (m0 + r) * 1024 + k0 + c * 8, As + (i * 256 + w * 64) * 8);
      async_copy16(B + (n0 + r) * 1024 + k0 + c * 8, Bs + (i * 256 + w * 64) * 8);
    }
    __syncthreads();
#pragma unroll
    for (int ks = 0; ks < 2; ++ks) {
      half8 af[4], bf[4];
#pragma unroll
      for (int mt = 0; mt < 4; ++mt)
        af[mt] = *(const half8*)(As + (wm * 64 + mt * 16 + l4) * 64 +
                                 (((ks * 4 + quad) ^ (l4 & 7)) * 8));
#pragma unroll
      for (int nt = 0; nt < 4; ++nt)
        bf[nt] = *(const half8*)(Bs + (wn * 64 + nt * 16 + l4) * 64 +
                                 (((ks * 4 + quad) ^ (l4 & 7)) * 8));
#pragma unroll
      for (int mt = 0; mt < 4; ++mt)
#pragma unroll
        for (int nt = 0; nt < 4; ++nt)
          acc[mt][nt] = __builtin_amdgcn_mfma_f32_16x16x32_f16(af[mt], bf[nt], acc[mt][nt], 0, 0, 0);
    }
    __syncthreads();
  }

  // epilogue: bias (+RoPE) in C-layout -> LDS tile -> coalesced half8 stores.
  // q,k: tile[m][n], store [bh][s][d]. V: tile[n][m], store V^T [bh][d][s].
  _Float16* tile = smem;                    // [128][132]
#pragma unroll
  for (int nt = 0; nt < 4; ++nt) {
    const int n = n0 + wn * 64 + nt * 16 + l4;
    const float bval = bias[n];
    const int hh = n >> 6;
    float c_ = 1.f, ss = 0.f;
    if (dorope) {
      const float freq = __expf((float)(n & 31) * -0.28782314f);  // ln(1e4)/32
      float s_;
      __sincosf((float)hh * freq, &s_, &c_);
      ss = (n & 1) ? s_ : -s_;
    }
#pragma unroll
    for (int mt = 0; mt < 4; ++mt)
#pragma unroll
      for (int r = 0; r < 4; ++r) {
        float val = acc[mt][nt][r] + bval;
        const float prt = __shfl_xor(val, 1);
        if (dorope) val = (val * c_ + prt * ss) * scl;
        const int ml = wm * 64 + mt * 16 + quad * 4 + r;
        const int nl = wn * 64 + nt * 16 + l4;
        if (z == 2) tile[nl * 132 + ml] = (_Float16)val;   // transposed
        else        tile[ml * 132 + nl] = (_Float16)val;
      }
  }
  __syncthreads();
  if (z == 2) {
#pragma unroll
    for (int j = 0; j < 8; ++j) {
      const int idx = j * 256 + tid;        // 128 d-rows x 16 s-chunks
      const int row = idx >> 4, cb = idx & 15;
      const int n = n0 + row, hh = n >> 6, dd = n & 63;
      const int m = m0 + cb * 8, bb = m >> 12, s = m & 4095;
      const half8 vals = *(const half8*)(tile + row * 132 + cb * 8);
      *(half8*)(out + (bb * 16 + hh) * 262144 + dd * 4096 + s) = vals;
    }
  } else {
#pragma unroll
    for (int j = 0; j < 8; ++j) {
      const int idx = j * 256 + tid;        // 128 s-rows x 16 d-chunks
      const int row = idx >> 4, cb = idx & 15;
      const int n = n0 + cb * 8, hh = n >> 6, dd = n & 63;
      const int m = m0 + row, bb = m >> 12, s = m & 4095;
      const half8 vals = *(const half8*)(tile + row * 132 + cb * 8);
      *(half8*)(out + ((bb * 16 + hh) * 4096 + s) * 64 + dd) = vals;
    }
  }
}

// ---------------------------------------------------------------- out GEMM
__global__ __launch_bounds__(256, 2) void gemm_out_kernel(
    const _Float16* __restrict__ A, const _Float16* __restrict__ B,
    const float* __restrict__ bias, float* __restrict__ out) {
  __shared__ _Float16 smem[16384];
  _Float16* As = smem;
  _Float16* Bs = smem + 8192;

  const int tid = threadIdx.x;
  const int w = tid >> 6, lane = tid & 63;
  const int l4 = lane & 15, quad = lane >> 4;
  const int wm = w & 1, wn = w >> 1;

  const int bid = blockIdx.x;
  const int xcd = bid & 7, li = bid >> 3;   // li in 0..63
  const int n_l = li >> 3, m_l = li & 7;
  const int m0 = (xcd * 8 + m_l) * 128;
  const int n0 = n_l * 128;

  const floatx4 zero = {0.f, 0.f, 0.f, 0.f};
  floatx4 acc[4][4];
#pragma unroll
  for (int i = 0; i < 4; ++i)
#pragma unroll
    for (int j = 0; j < 4; ++j) acc[i][j] = zero;

  for (int kt = 0; kt < 16; ++kt) {
    const int k0 = kt * 64;
#pragma unroll
    for (int i = 0; i < 4; ++i) {
      const int p = i * 256 + tid;
      const int r = p >> 3;
      const int c = (p & 7) ^ (r & 7);
      async_copy16(A + (m0 + r) * 1024 + k0 + c * 8, As + (i * 256 + w * 64) * 8);
      async_copy16(B + (n0 + r) * 1024 + k0 + c * 8, Bs + (i * 256 + w * 64) * 8);
    }
    __syncthreads();
#pragma unroll
    for (int ks = 0; ks < 2; ++ks) {
      half8 af[4], bf[4];
#pragma unroll
      for (int mt = 0; mt < 4; ++mt)
        af[mt] = *(const half8*)(As + (wm * 64 + mt * 16 + l4) * 64 +
                                 (((ks * 4 + quad) ^ (l4 & 7)) * 8));
#pragma unroll
      for (int nt = 0; nt < 4; ++nt)
        bf[nt] = *(const half8*)(Bs + (wn * 64 + nt * 16 + l4) * 64 +
                                 (((ks * 4 + quad) ^ (l4 & 7)) * 8));
#pragma unroll
      for (int mt = 0; mt < 4; ++mt)
#pragma unroll
        for (int nt = 0; nt < 4; ++nt)
          acc[mt][nt] = __builtin_amdgcn_mfma_f32_16x16x32_f16(af[mt], bf[nt], acc[mt][nt], 0, 0, 0);
    }
    __syncthreads();
  }

#pragma unroll
  for (int nt = 0; nt < 4; ++nt) {
    const int n = n0 + wn * 64 + nt * 16 + l4;
    const float bval = bias[n];
#pragma unroll
    for (int mt = 0; mt < 4; ++mt)
#pragma unroll
      for (int r = 0; r < 4; ++r) {
        const int m = m0 + wm * 64 + mt * 16 + quad * 4 + r;
        out[m * 1024 + n] = acc[mt][nt][r] + bval;
      }
  }
}

// ---------------------------------------------------------------- attention
// S^T formulation: ST = K*Q^T per 64-key half-tile; ST C-layout IS the
// B-operand layout of mfma_f32_16x16x16f16 -> P feeds PV from registers.
// R9: 128 queries/block, grid 1024 (= 4 blocks/CU, 16 waves/CU), XCD-swizzled
// bh mapping (xcd owns 4 heads -> KV L2-resident). 5 kv-tiles/block.
// Wave-uniform exact band tests: skip 64-key half-tiles fully outside
// |key-query|<=256 for this wave's 32 queries; mask only true straddles.
// Softmax: STATIC shift P = exp2(S-4); lane-local l, cross-quad reduce at end.
__global__ __launch_bounds__(256, 4) void attn_kernel(
    const _Float16* __restrict__ qg, const _Float16* __restrict__ kg,
    const _Float16* __restrict__ vtg, _Float16* __restrict__ ctx) {
  __shared__ _Float16 Ks[128 * 64];   // [key][d]
  __shared__ _Float16 Vs[64 * 128];   // [d][key] (from vt)

  const int tid = threadIdx.x;
  const int w = tid >> 6, lane = tid & 63;
  const int l4 = lane & 15, quad = lane >> 4;

  const int bid = blockIdx.x;
  const int li = bid >> 3;                  // 0..127
  const int bh = (bid & 7) * 4 + (li >> 5); // XCD owns 4 consecutive bh
  const int q0 = (li & 31) * 128;

  const _Float16* qbh = qg + bh * 262144;
  const _Float16* kbh = kg + bh * 262144;
  const _Float16* vbh = vtg + bh * 262144;

  // Q as B-operand frags: query = q0 + w*32 + nt*16 + l4
  half8 qf[2][2];
#pragma unroll
  for (int nt = 0; nt < 2; ++nt)
#pragma unroll
    for (int ks = 0; ks < 2; ++ks)
      qf[nt][ks] = *(const half8*)(qbh + (q0 + w * 32 + nt * 16 + l4) * 64 +
                                   ks * 32 + quad * 8);

  const floatx4 zero = {0.f, 0.f, 0.f, 0.f};
  floatx4 OT[4][2];                  // [d-tile][q-tile]
  float l_st[2] = {0.f, 0.f};        // lane-local partial (this quad's keys)
#pragma unroll
  for (int md = 0; md < 4; ++md)
#pragma unroll
    for (int nt = 0; nt < 2; ++nt) OT[md][nt] = zero;

  const int qbase = q0 + w * 32;     // this wave's 32 queries

  for (int t = 0; t < 5; ++t) {
    const int kv0 = q0 - 256 + t * 128;
    if (kv0 < 0 || kv0 >= 4096) continue;  // block-uniform

#pragma unroll
    for (int i = 0; i < 4; ++i) {
      const int p = i * 256 + tid;
      const int rk = p >> 3, ck = (p & 7) ^ (rk & 7);
      async_copy16(kbh + (kv0 + rk) * 64 + ck * 8, Ks + (i * 256 + w * 64) * 8);
      const int rv = p >> 4, cv = (p & 15) ^ (rv & 7);
      async_copy16(vbh + rv * 4096 + kv0 + cv * 8, Vs + (i * 256 + w * 64) * 8);
    }
    __syncthreads();

#pragma unroll
    for (int hf = 0; hf < 2; ++hf) {
      const int kb = hf * 64;
      const int k_lo = kv0 + kb, k_hi = k_lo + 63;
      // wave-uniform: all 64 keys outside band for all 32 queries -> skip
      if (k_lo - (qbase + 31) > 256 || k_hi - qbase < -256) continue;
      const bool needm = (k_lo - (qbase + 31) < -256) || (k_hi - qbase > 256);

      floatx4 ST[4][2];
#pragma unroll
      for (int m = 0; m < 4; ++m)
#pragma unroll
        for (int nt = 0; nt < 2; ++nt) ST[m][nt] = zero;
#pragma unroll
      for (int ks = 0; ks < 2; ++ks)
#pragma unroll
        for (int m = 0; m < 4; ++m) {
          const half8 kf = *(const half8*)(Ks + (kb + m * 16 + l4) * 64 +
                                           ((ks * 4 + quad) ^ (l4 & 7)) * 8);
#pragma unroll
          for (int nt = 0; nt < 2; ++nt)
            ST[m][nt] = __builtin_amdgcn_mfma_f32_16x16x32_f16(kf, qf[nt][ks], ST[m][nt], 0, 0, 0);
        }

      if (needm) {  // band mask |key - query| <= 256
#pragma unroll
        for (int m = 0; m < 4; ++m)
#pragma unroll
          for (int r = 0; r < 4; ++r) {
            const int key = kv0 + kb + m * 16 + quad * 4 + r;
#pragma unroll
            for (int nt = 0; nt < 2; ++nt) {
              const int d = key - (qbase + nt * 16 + l4);
              if (d < -256 || d > 256) ST[m][nt][r] = -1e30f;
            }
          }
      }

      // P = exp2(S - 4); lane-local l accumulation (no max, no rescale)
#pragma unroll
      for (int nt = 0; nt < 2; ++nt) {
        float rs = 0.f;
#pragma unroll
        for (int m = 0; m < 4; ++m)
#pragma unroll
          for (int r = 0; r < 4; ++r) {
            const float pv = exp2f(ST[m][nt][r] - 4.0f);
            ST[m][nt][r] = pv;
            rs += pv;
          }
        l_st[nt] += rs;
      }

      // O^T += V^T P^T; P B-frag = packed ST C-frag (k=quad*4+j)
#pragma unroll
      for (int m = 0; m < 4; ++m) {
        half4v pb[2];
#pragma unroll
        for (int nt = 0; nt < 2; ++nt) {
          const auto lo = __builtin_amdgcn_cvt_pkrtz(ST[m][nt][0], ST[m][nt][1]);
          const auto hi = __builtin_amdgcn_cvt_pkrtz(ST[m][nt][2], ST[m][nt][3]);
          pb[nt][0] = (_Float16)lo[0]; pb[nt][1] = (_Float16)lo[1];
          pb[nt][2] = (_Float16)hi[0]; pb[nt][3] = (_Float16)hi[1];
        }
#pragma unroll
        for (int md = 0; md < 4; ++md) {
          const half4v vf = *(const half4v*)(Vs + (md * 16 + l4) * 128 +
                                             (((hf * 8 + m * 2 + (quad >> 1)) ^ (l4 & 7)) * 8 +
                                              (quad & 1) * 4));
#pragma unroll
          for (int nt = 0; nt < 2; ++nt)
            OT[md][nt] = __builtin_amdgcn_mfma_f32_16x16x16f16(vf, pb[nt], OT[md][nt], 0, 0, 0);
        }
      }
    }
    __syncthreads();  // protect Ks/Vs before next tile's staging
  }

  // epilogue: reduce l across quads (keys were quad-distributed), then scale.
  const int b = bh >> 4, hh = bh & 15;
#pragma unroll
  for (int nt = 0; nt < 2; ++nt) {
    float lt = l_st[nt];
    lt += __shfl_xor(lt, 16);
    lt += __shfl_xor(lt, 32);
    const float inv_l = 1.f / lt;
    const int s = q0 + w * 32 + nt * 16 + l4;
#pragma unroll
    for (int md = 0; md < 4; ++md) {
      half4v o;
#pragma unroll
      for (int r = 0; r < 4; ++r) o[r] = (_Float16)(OT[md][nt][r] * inv_l);
      *(half4v*)(ctx + (b * 4096 + s) * 1024 + hh * 64 + md * 16 + quad * 4) = o;
    }
  }
}

// ---------------------------------------------------------------- launch
extern "C" void kernel_launch(void* const* d_in, const int* in_sizes, int n_in,
                              void* d_out, int out_size, void* d_ws, size_t ws_size,
                              hipStream_t stream) {
  const float* x  = (const float*)d_in[0];
  const float* Wq = (const float*)d_in[1];
  const float* bq = (const float*)d_in[2];
  const float* Wk = (const float*)d_in[3];
  const float* bk = (const float*)d_in[4];
  const float* Wv = (const float*)d_in[5];
  const float* bv = (const float*)d_in[6];
  const float* Wo = (const float*)d_in[7];
  const float* bo = (const float*)d_in[8];

  _Float16* ws   = (_Float16*)d_ws;       // all offsets in halfs
  _Float16* xh   = ws;                    // 8388608
  _Float16* wqh  = ws + 8388608;          // 1048576 each
  _Float16* wkh  = ws + 9437184;
  _Float16* wvh  = ws + 10485760;
  _Float16* woh  = ws + 11534336;
  _Float16* qh   = ws + 12582912;         // [b,h,s,d] fp16, rope+scale applied
  _Float16* kh   = ws + 20971520;         // [b,h,s,d] fp16, rope applied
  _Float16* vth  = ws + 29360128;         // [b,h,d,s] fp16 (written directly)
  _Float16* ctxh = xh;                    // reuse: x dead after QKV GEMM

  convert_kernel<<<12288, 256, 0, stream>>>(x, Wq, Wk, Wv, Wo, ws);
  gemm_qkv_kernel<<<1536, 256, 0, stream>>>(xh, wqh, wkh, wvh,
                                            bq, bk, bv, qh, kh, vth);
  attn_kernel<<<1024, 256, 0, stream>>>(qh, kh, vth, ctxh);
  gemm_out_kernel<<<512, 256, 0, stream>>>(ctxh, woh, bo, (float*)d_out);
}

// Round 3
// 226.006 us; speedup vs baseline: 1.1420x; 1.1214x over previous
//
#include <hip/hip_runtime.h>

// LongformerAttention on MI355X (gfx950), fp16 MFMA pipeline, round 10.
// R10: GEMMs = R7 (known-good; cross-session clocks vary +-25%, so qkv's
// 67 vs 85 us is noise — MfmaUtil ~33% is the stable anchor). Attention:
// back to 256 q/block (R9's 128 q/block raised staged KV bytes/query 1.5->2.5
// KB and regressed; attn staging is the bottleneck), now with the staging
// serialization FIXED:
//   - double-buffered Ks/Vs (2x32 KB = 64 KB LDS, 2 blocks/CU), stage(t+1)
//     issued BEFORE waiting on tile t; counted s_waitcnt vmcnt(8) (8 loads/
//     thread/tile; t+1's 8 stay in flight) + raw s_barrier. Trailing barrier
//     is lgkmcnt(0)+sched_barrier(0)+s_barrier — NOT __syncthreads, which
//     drains vmcnt(0) and would kill the overlap (the m97-structure stall).
//   - exact per-wave band tests (skip 64-key half-tiles fully outside
//     |key-query|<=256 for the wave's 32 queries; mask only true straddles) —
//     finer than R7's static (t,sub) table, skips more edge work.
//   - XCD-grouped bh: xcd=bid&7 owns 4 heads -> 4 MB KV = L2-resident.
// Softmax unchanged: STATIC shift P = exp2(S-4), lane-local l, quad-reduce
// at epilogue.

typedef _Float16 half8 __attribute__((ext_vector_type(8)));
typedef _Float16 half4v __attribute__((ext_vector_type(4)));
typedef float floatx4 __attribute__((ext_vector_type(4)));

typedef __attribute__((address_space(3))) unsigned int lds_u32;
typedef const __attribute__((address_space(1))) unsigned int glb_u32;

__device__ __forceinline__ void async_copy16(const void* g, void* l) {
  // global -> LDS direct, 16 B/lane. LDS dest = wave-uniform base + lane*16.
  __builtin_amdgcn_global_load_lds((glb_u32*)g, (lds_u32*)l, 16, 0, 0);
}

// ---------------------------------------------------------------- convert
__global__ __launch_bounds__(256) void convert_kernel(
    const float* __restrict__ x, const float* __restrict__ wq,
    const float* __restrict__ wk, const float* __restrict__ wv,
    const float* __restrict__ wo, _Float16* __restrict__ dst) {
  const int e0 = (blockIdx.x * 256 + threadIdx.x) * 4;
  const float* src; int off;
  if      (e0 <  8388608) { src = x;  off = e0; }
  else if (e0 <  9437184) { src = wq; off = e0 -  8388608; }
  else if (e0 < 10485760) { src = wk; off = e0 -  9437184; }
  else if (e0 < 11534336) { src = wv; off = e0 - 10485760; }
  else                    { src = wo; off = e0 - 11534336; }
  const float4 f = *(const float4*)(src + off);
  half4v h;
  h[0] = (_Float16)f.x; h[1] = (_Float16)f.y;
  h[2] = (_Float16)f.z; h[3] = (_Float16)f.w;
  *(half4v*)(dst + e0) = h;
}

// ---------------------------------------------------------------- QKV GEMM
// out[m,n] = sum_k A[m,k]*W[n,k] + bias[n]; RoPE fused in epilogue for q,k
// (pair (n,n^1) in adjacent l4 lanes -> __shfl_xor(val,1)); q scaled log2e/8.
// z==2 (V): epilogue LDS tile stored transposed, output written as V^T
// [bh][d][s] directly.
__global__ __launch_bounds__(256, 2) void gemm_qkv_kernel(
    const _Float16* __restrict__ A, const _Float16* __restrict__ w0,
    const _Float16* __restrict__ w1, const _Float16* __restrict__ w2,
    const float* __restrict__ b0, const float* __restrict__ b1,
    const float* __restrict__ b2, _Float16* __restrict__ o0,
    _Float16* __restrict__ o1, _Float16* __restrict__ o2) {
  __shared__ _Float16 smem[17408];          // staging 32 KB / epi tile 33.8 KB
  _Float16* As = smem;                      // [128][64] chunk-swizzled
  _Float16* Bs = smem + 8192;

  const int tid = threadIdx.x;
  const int w = tid >> 6, lane = tid & 63;
  const int l4 = lane & 15, quad = lane >> 4;
  const int wm = w & 1, wn = w >> 1;

  const int bid = blockIdx.x;
  const int xcd = bid & 7, li = bid >> 3;   // li in 0..191
  const int z = li >> 6, r_ = li & 63;
  const int n_l = r_ >> 3, m_l = r_ & 7;
  const int m0 = (xcd * 8 + m_l) * 128;
  const int n0 = n_l * 128;

  const _Float16* B; const float* bias; _Float16* out;
  if (z == 0)      { B = w0; bias = b0; out = o0; }
  else if (z == 1) { B = w1; bias = b1; out = o1; }
  else             { B = w2; bias = b2; out = o2; }
  const bool dorope = z < 2;
  const float scl = (z == 0) ? 0.18033688f : 1.0f;  // log2e/8

  const floatx4 zero = {0.f, 0.f, 0.f, 0.f};
  floatx4 acc[4][4];
#pragma unroll
  for (int i = 0; i < 4; ++i)
#pragma unroll
    for (int j = 0; j < 4; ++j) acc[i][j] = zero;

  for (int kt = 0; kt < 16; ++kt) {
    const int k0 = kt * 64;
#pragma unroll
    for (int i = 0; i < 4; ++i) {
      const int p = i * 256 + tid;          // 128 rows x 8 chunks
      const int r = p >> 3;
      const int c = (p & 7) ^ (r & 7);      // 3-bit XOR chunk swizzle
      async_copy16(A + (m0 + r) * 1024 + k0 + c * 8, As + (i * 256 + w * 64) * 8);
      async_copy16(B + (n0 + r) * 1024 + k0 + c * 8, Bs + (i * 256 + w * 64) * 8);
    }
    __syncthreads();
#pragma unroll
    for (int ks = 0; ks < 2; ++ks) {
      half8 af[4], bf[4];
#pragma unroll
      for (int mt = 0; mt < 4; ++mt)
        af[mt] = *(const half8*)(As + (wm * 64 + mt * 16 + l4) * 64 +
                                 (((ks * 4 + quad) ^ (l4 & 7)) * 8));
#pragma unroll
      for (int nt = 0; nt < 4; ++nt)
        bf[nt] = *(const half8*)(Bs + (wn * 64 + nt * 16 + l4) * 64 +
                                 (((ks * 4 + quad) ^ (l4 & 7)) * 8));
#pragma unroll
      for (int mt = 0; mt < 4; ++mt)
#pragma unroll
        for (int nt = 0; nt < 4; ++nt)
          acc[mt][nt] = __builtin_amdgcn_mfma_f32_16x16x32_f16(af[mt], bf[nt], acc[mt][nt], 0, 0, 0);
    }
    __syncthreads();
  }

  // epilogue: bias (+RoPE) in C-layout -> LDS tile -> coalesced half8 stores.
  // q,k: tile[m][n], store [bh][s][d]. V: tile[n][m], store V^T [bh][d][s].
  _Float16* tile = smem;                    // [128][132]
#pragma unroll
  for (int nt = 0; nt < 4; ++nt) {
    const int n = n0 + wn * 64 + nt * 16 + l4;
    const float bval = bias[n];
    const int hh = n >> 6;
    float c_ = 1.f, ss = 0.f;
    if (dorope) {
      const float freq = __expf((float)(n & 31) * -0.28782314f);  // ln(1e4)/32
      float s_;
      __sincosf((float)hh * freq, &s_, &c_);
      ss = (n & 1) ? s_ : -s_;
    }
#pragma unroll
    for (int mt = 0; mt < 4; ++mt)
#pragma unroll
      for (int r = 0; r < 4; ++r) {
        float val = acc[mt][nt][r] + bval;
        const float prt = __shfl_xor(val, 1);
        if (dorope) val = (val * c_ + prt * ss) * scl;
        const int ml = wm * 64 + mt * 16 + quad * 4 + r;
        const int nl = wn * 64 + nt * 16 + l4;
        if (z == 2) tile[nl * 132 + ml] = (_Float16)val;   // transposed
        else        tile[ml * 132 + nl] = (_Float16)val;
      }
  }
  __syncthreads();
  if (z == 2) {
#pragma unroll
    for (int j = 0; j < 8; ++j) {
      const int idx = j * 256 + tid;        // 128 d-rows x 16 s-chunks
      const int row = idx >> 4, cb = idx & 15;
      const int n = n0 + row, hh = n >> 6, dd = n & 63;
      const int m = m0 + cb * 8, bb = m >> 12, s = m & 4095;
      const half8 vals = *(const half8*)(tile + row * 132 + cb * 8);
      *(half8*)(out + (bb * 16 + hh) * 262144 + dd * 4096 + s) = vals;
    }
  } else {
#pragma unroll
    for (int j = 0; j < 8; ++j) {
      const int idx = j * 256 + tid;        // 128 s-rows x 16 d-chunks
      const int row = idx >> 4, cb = idx & 15;
      const int n = n0 + cb * 8, hh = n >> 6, dd = n & 63;
      const int m = m0 + row, bb = m >> 12, s = m & 4095;
      const half8 vals = *(const half8*)(tile + row * 132 + cb * 8);
      *(half8*)(out + ((bb * 16 + hh) * 4096 + s) * 64 + dd) = vals;
    }
  }
}

// ---------------------------------------------------------------- out GEMM
__global__ __launch_bounds__(256, 2) void gemm_out_kernel(
    const _Float16* __restrict__ A, const _Float16* __restrict__ B,
    const float* __restrict__ bias, float* __restrict__ out) {
  __shared__ _Float16 smem[16384];
  _Float16* As = smem;
  _Float16* Bs = smem + 8192;

  const int tid = threadIdx.x;
  const int w = tid >> 6, lane = tid & 63;
  const int l4 = lane & 15, quad = lane >> 4;
  const int wm = w & 1, wn = w >> 1;

  const int bid = blockIdx.x;
  const int xcd = bid & 7, li = bid >> 3;   // li in 0..63
  const int n_l = li >> 3, m_l = li & 7;
  const int m0 = (xcd * 8 + m_l) * 128;
  const int n0 = n_l * 128;

  const floatx4 zero = {0.f, 0.f, 0.f, 0.f};
  floatx4 acc[4][4];
#pragma unroll
  for (int i = 0; i < 4; ++i)
#pragma unroll
    for (int j = 0; j < 4; ++j) acc[i][j] = zero;

  for (int kt = 0; kt < 16; ++kt) {
    const int k0 = kt * 64;
#pragma unroll
    for (int i = 0; i < 4; ++i) {
      const int p = i * 256 + tid;
      const int r = p >> 3;
      const int c = (p & 7) ^ (r & 7);
      async_copy16(A + (m0 + r) * 1024 + k0 + c * 8, As + (i * 256 + w * 64) * 8);
      async_copy16(B + (n0 + r) * 1024 + k0 + c * 8, Bs + (i * 256 + w * 64) * 8);
    }
    __syncthreads();
#pragma unroll
    for (int ks = 0; ks < 2; ++ks) {
      half8 af[4], bf[4];
#pragma unroll
      for (int mt = 0; mt < 4; ++mt)
        af[mt] = *(const half8*)(As + (wm * 64 + mt * 16 + l4) * 64 +
                                 (((ks * 4 + quad) ^ (l4 & 7)) * 8));
#pragma unroll
      for (int nt = 0; nt < 4; ++nt)
        bf[nt] = *(const half8*)(Bs + (wn * 64 + nt * 16 + l4) * 64 +
                                 (((ks * 4 + quad) ^ (l4 & 7)) * 8));
#pragma unroll
      for (int mt = 0; mt < 4; ++mt)
#pragma unroll
        for (int nt = 0; nt < 4; ++nt)
          acc[mt][nt] = __builtin_amdgcn_mfma_f32_16x16x32_f16(af[mt], bf[nt], acc[mt][nt], 0, 0, 0);
    }
    __syncthreads();
  }

#pragma unroll
  for (int nt = 0; nt < 4; ++nt) {
    const int n = n0 + wn * 64 + nt * 16 + l4;
    const float bval = bias[n];
#pragma unroll
    for (int mt = 0; mt < 4; ++mt)
#pragma unroll
      for (int r = 0; r < 4; ++r) {
        const int m = m0 + wm * 64 + mt * 16 + quad * 4 + r;
        out[m * 1024 + n] = acc[mt][nt][r] + bval;
      }
  }
}

// ---------------------------------------------------------------- attention
// S^T formulation: ST = K*Q^T per 64-key half-tile; ST C-layout IS the
// B-operand layout of mfma_f32_16x16x16f16 -> P feeds PV from registers.
// R10: 256 q/block (grid 512), double-buffered KV staging with stage-ahead
// + counted vmcnt(8) (8 global_load_lds per thread per tile) -> staging of
// tile t+1 overlaps compute of tile t. Raw s_barrier (no vmcnt(0) drain).
// Exact per-wave band skip/mask. XCD-grouped bh (4 heads/XCD, KV L2-fit).
__global__ __launch_bounds__(256, 2) void attn_kernel(
    const _Float16* __restrict__ qg, const _Float16* __restrict__ kg,
    const _Float16* __restrict__ vtg, _Float16* __restrict__ ctx) {
  __shared__ _Float16 Ks[2][128 * 64];   // [buf][key][d]
  __shared__ _Float16 Vs[2][64 * 128];   // [buf][d][key] (from vt)

  const int tid = threadIdx.x;
  const int w = tid >> 6, lane = tid & 63;
  const int l4 = lane & 15, quad = lane >> 4;

  const int bid = blockIdx.x;
  const int xcd = bid & 7, li = bid >> 3;   // li 0..63
  const int bh = xcd * 4 + (li >> 4);       // XCD owns 4 heads -> KV L2-fit
  const int q0 = (li & 15) * 256;

  const _Float16* qbh = qg + bh * 262144;
  const _Float16* kbh = kg + bh * 262144;
  const _Float16* vbh = vtg + bh * 262144;

  // Q as B-operand frags: query = q0 + sub*128 + w*32 + nt*16 + l4
  half8 qf[2][2][2];
#pragma unroll
  for (int sub = 0; sub < 2; ++sub)
#pragma unroll
    for (int nt = 0; nt < 2; ++nt)
#pragma unroll
      for (int ks = 0; ks < 2; ++ks)
        qf[sub][nt][ks] = *(const half8*)(qbh + (q0 + sub * 128 + w * 32 + nt * 16 + l4) * 64 +
                                          ks * 32 + quad * 8);

  const floatx4 zero = {0.f, 0.f, 0.f, 0.f};
  floatx4 OT[2][4][2];               // [sub][d-tile][q-tile]
  float l_st[2][2];                  // lane-local partial (this quad's keys)
#pragma unroll
  for (int sub = 0; sub < 2; ++sub) {
#pragma unroll
    for (int md = 0; md < 4; ++md)
#pragma unroll
      for (int nt = 0; nt < 2; ++nt) OT[sub][md][nt] = zero;
#pragma unroll
    for (int nt = 0; nt < 2; ++nt) l_st[sub][nt] = 0.f;
  }

  // valid kv-tile range: kv0(t) = q0 - 256 + t*128 in [0, 3968]
  const int tb = (q0 == 0) ? 2 : 0;
  const int te = (q0 == 3840) ? 3 : 5;

  // stage one 128-key tile (K + V^T slab) into buffer b_: 8 loads/thread.
  auto stage = [&](int b_, int kv0_) {
#pragma unroll
    for (int i = 0; i < 4; ++i) {
      const int p = i * 256 + tid;
      const int rk = p >> 3, ck = (p & 7) ^ (rk & 7);
      async_copy16(kbh + (kv0_ + rk) * 64 + ck * 8, &Ks[b_][(i * 256 + w * 64) * 8]);
      const int rv = p >> 4, cv = (p & 15) ^ (rv & 7);
      async_copy16(vbh + rv * 4096 + kv0_ + cv * 8, &Vs[b_][(i * 256 + w * 64) * 8]);
    }
  };

  stage(tb & 1, q0 - 256 + tb * 128);

  for (int t = tb; t <= te; ++t) {
    const int kv0 = q0 - 256 + t * 128;
    if (t < te) {
      stage((t + 1) & 1, kv0 + 128);
      asm volatile("s_waitcnt vmcnt(8)" ::: "memory");  // tile t landed; t+1 in flight
    } else {
      asm volatile("s_waitcnt vmcnt(0)" ::: "memory");  // last tile: drain
    }
    __builtin_amdgcn_s_barrier();
    const _Float16* Kc = Ks[t & 1];
    const _Float16* Vc = Vs[t & 1];

#pragma unroll
    for (int sub = 0; sub < 2; ++sub) {
      const int qbase = q0 + sub * 128 + w * 32;   // this wave's 32 queries
#pragma unroll
      for (int hf = 0; hf < 2; ++hf) {
        const int kb = hf * 64;
        const int k_lo = kv0 + kb, k_hi = k_lo + 63;
        // wave-uniform: all 64 keys outside band for all 32 queries -> skip
        if (k_lo - (qbase + 31) > 256 || k_hi - qbase < -256) continue;
        const bool needm = (k_lo - (qbase + 31) < -256) || (k_hi - qbase > 256);

        floatx4 ST[4][2];
#pragma unroll
        for (int m = 0; m < 4; ++m)
#pragma unroll
          for (int nt = 0; nt < 2; ++nt) ST[m][nt] = zero;
#pragma unroll
        for (int ks = 0; ks < 2; ++ks)
#pragma unroll
          for (int m = 0; m < 4; ++m) {
            const half8 kf = *(const half8*)(Kc + (kb + m * 16 + l4) * 64 +
                                             ((ks * 4 + quad) ^ (l4 & 7)) * 8);
#pragma unroll
            for (int nt = 0; nt < 2; ++nt)
              ST[m][nt] = __builtin_amdgcn_mfma_f32_16x16x32_f16(kf, qf[sub][nt][ks], ST[m][nt], 0, 0, 0);
          }

        if (needm) {  // band mask |key - query| <= 256
#pragma unroll
          for (int m = 0; m < 4; ++m)
#pragma unroll
            for (int r = 0; r < 4; ++r) {
              const int key = kv0 + kb + m * 16 + quad * 4 + r;
#pragma unroll
              for (int nt = 0; nt < 2; ++nt) {
                const int d = key - (qbase + nt * 16 + l4);
                if (d < -256 || d > 256) ST[m][nt][r] = -1e30f;
              }
            }
        }

        // P = exp2(S - 4); lane-local l accumulation (no max, no rescale)
#pragma unroll
        for (int nt = 0; nt < 2; ++nt) {
          float rs = 0.f;
#pragma unroll
          for (int m = 0; m < 4; ++m)
#pragma unroll
            for (int r = 0; r < 4; ++r) {
              const float pv = exp2f(ST[m][nt][r] - 4.0f);
              ST[m][nt][r] = pv;
              rs += pv;
            }
          l_st[sub][nt] += rs;
        }

        // O^T += V^T P^T; P B-frag = packed ST C-frag (k=quad*4+j)
#pragma unroll
        for (int m = 0; m < 4; ++m) {
          half4v pb[2];
#pragma unroll
          for (int nt = 0; nt < 2; ++nt) {
            const auto lo = __builtin_amdgcn_cvt_pkrtz(ST[m][nt][0], ST[m][nt][1]);
            const auto hi = __builtin_amdgcn_cvt_pkrtz(ST[m][nt][2], ST[m][nt][3]);
            pb[nt][0] = (_Float16)lo[0]; pb[nt][1] = (_Float16)lo[1];
            pb[nt][2] = (_Float16)hi[0]; pb[nt][3] = (_Float16)hi[1];
          }
#pragma unroll
          for (int md = 0; md < 4; ++md) {
            const half4v vf = *(const half4v*)(Vc + (md * 16 + l4) * 128 +
                                               (((hf * 8 + m * 2 + (quad >> 1)) ^ (l4 & 7)) * 8 +
                                                (quad & 1) * 4));
#pragma unroll
            for (int nt = 0; nt < 2; ++nt)
              OT[sub][md][nt] = __builtin_amdgcn_mfma_f32_16x16x16f16(vf, pb[nt], OT[sub][md][nt], 0, 0, 0);
          }
        }
      }
    }

    if (t < te) {
      // trailing barrier: my ds_reads of this buffer must retire before any
      // wave stages into it next iteration. NOT __syncthreads (vmcnt drain).
      asm volatile("s_waitcnt lgkmcnt(0)" ::: "memory");
      __builtin_amdgcn_sched_barrier(0);
      __builtin_amdgcn_s_barrier();
    }
  }

  // epilogue: reduce l across quads (keys were quad-distributed), then scale.
  const int b = bh >> 4, hh = bh & 15;
#pragma unroll
  for (int sub = 0; sub < 2; ++sub)
#pragma unroll
    for (int nt = 0; nt < 2; ++nt) {
      float lt = l_st[sub][nt];
      lt += __shfl_xor(lt, 16);
      lt += __shfl_xor(lt, 32);
      const float inv_l = 1.f / lt;
      const int s = q0 + sub * 128 + w * 32 + nt * 16 + l4;
#pragma unroll
      for (int md = 0; md < 4; ++md) {
        half4v o;
#pragma unroll
        for (int r = 0; r < 4; ++r) o[r] = (_Float16)(OT[sub][md][nt][r] * inv_l);
        *(half4v*)(ctx + (b * 4096 + s) * 1024 + hh * 64 + md * 16 + quad * 4) = o;
      }
    }
}

// ---------------------------------------------------------------- launch
extern "C" void kernel_launch(void* const* d_in, const int* in_sizes, int n_in,
                              void* d_out, int out_size, void* d_ws, size_t ws_size,
                              hipStream_t stream) {
  const float* x  = (const float*)d_in[0];
  const float* Wq = (const float*)d_in[1];
  const float* bq = (const float*)d_in[2];
  const float* Wk = (const float*)d_in[3];
  const float* bk = (const float*)d_in[4];
  const float* Wv = (const float*)d_in[5];
  const float* bv = (const float*)d_in[6];
  const float* Wo = (const float*)d_in[7];
  const float* bo = (const float*)d_in[8];

  _Float16* ws   = (_Float16*)d_ws;       // all offsets in halfs
  _Float16* xh   = ws;                    // 8388608
  _Float16* wqh  = ws + 8388608;          // 1048576 each
  _Float16* wkh  = ws + 9437184;
  _Float16* wvh  = ws + 10485760;
  _Float16* woh  = ws + 11534336;
  _Float16* qh   = ws + 12582912;         // [b,h,s,d] fp16, rope+scale applied
  _Float16* kh   = ws + 20971520;         // [b,h,s,d] fp16, rope applied
  _Float16* vth  = ws + 29360128;         // [b,h,d,s] fp16 (written directly)
  _Float16* ctxh = xh;                    // reuse: x dead after QKV GEMM

  convert_kernel<<<12288, 256, 0, stream>>>(x, Wq, Wk, Wv, Wo, ws);
  gemm_qkv_kernel<<<1536, 256, 0, stream>>>(xh, wqh, wkh, wvh,
                                            bq, bk, bv, qh, kh, vth);
  attn_kernel<<<512, 256, 0, stream>>>(qh, kh, vth, ctxh);
  gemm_out_kernel<<<512, 256, 0, stream>>>(ctxh, woh, bo, (float*)d_out);
}